// Round 1
// baseline (1232.966 us; speedup 1.0000x reference)
//
#include <hip/hip_runtime.h>

#define IN_CH 256
#define OUT_CH 64

// ---------------------------------------------------------------------------
// Dense transform: out[n][64] = relu(feat[n][256] @ W[256][64] + bias[64])
// Register-tiled: block = 256 threads, 64 rows x 64 ch tile, 4x4 per thread.
// LDS padded to stride 68 floats (multiple of 4 for float4 alignment; breaks
// power-of-2 bank stride).
// ---------------------------------------------------------------------------
__global__ __launch_bounds__(256) void gemm_relu_kernel(
    const float* __restrict__ feat, const float* __restrict__ W,
    const float* __restrict__ bias, float* __restrict__ out, int n)
{
    constexpr int BM = 64, BK = 64, PAD = 68;
    __shared__ float As[BM][PAD];   // feature tile [row][k]
    __shared__ float Bs[BK][PAD];   // weight tile  [k][ch]

    const int tid = threadIdx.x;
    const int tx = tid & 15;        // channel group (4 ch each)
    const int ty = tid >> 4;        // row group (4 rows each)
    const int row0 = blockIdx.x * BM;

    float acc[4][4];
#pragma unroll
    for (int i = 0; i < 4; ++i)
#pragma unroll
        for (int j = 0; j < 4; ++j) acc[i][j] = 0.f;

    const float4* feat4 = (const float4*)feat;
    const float4* W4    = (const float4*)W;

    for (int k0 = 0; k0 < IN_CH; k0 += BK) {
        // Stage tiles: 64x64 floats each = 1024 float4 = 4 per thread.
#pragma unroll
        for (int i = 0; i < 4; ++i) {
            int li = tid + i * 256;
            int r  = li >> 4;        // 16 float4 per row
            int c4 = li & 15;
            int grow = row0 + r;
            float4 v = make_float4(0.f, 0.f, 0.f, 0.f);
            if (grow < n) v = feat4[(size_t)grow * (IN_CH / 4) + (k0 >> 2) + c4];
            *(float4*)&As[r][c4 * 4] = v;
            float4 w = W4[(size_t)(k0 + r) * (OUT_CH / 4) + c4];
            *(float4*)&Bs[r][c4 * 4] = w;
        }
        __syncthreads();

#pragma unroll
        for (int kk = 0; kk < BK; ++kk) {
            float4 b = *(const float4*)&Bs[kk][tx * 4];
#pragma unroll
            for (int i = 0; i < 4; ++i) {
                float a = As[ty * 4 + i][kk];
                acc[i][0] += a * b.x;
                acc[i][1] += a * b.y;
                acc[i][2] += a * b.z;
                acc[i][3] += a * b.w;
            }
        }
        __syncthreads();
    }

    float4 bv = ((const float4*)bias)[tx];
#pragma unroll
    for (int i = 0; i < 4; ++i) {
        int grow = row0 + ty * 4 + i;
        if (grow < n) {
            float4 o;
            o.x = fmaxf(acc[i][0] + bv.x, 0.f);
            o.y = fmaxf(acc[i][1] + bv.y, 0.f);
            o.z = fmaxf(acc[i][2] + bv.z, 0.f);
            o.w = fmaxf(acc[i][3] + bv.w, 0.f);
            *(float4*)&out[(size_t)grow * OUT_CH + tx * 4] = o;
        }
    }
}

// ---------------------------------------------------------------------------
// One SpMM hop: dst[row[e]][c] += val[e] * src[col[e]][c]  (dst pre-zeroed)
// One wave per edge (lane = channel): index/value loads are wave-uniform
// broadcasts, the 256 B gather and the 64 atomics are lane-contiguous.
// ---------------------------------------------------------------------------
__global__ __launch_bounds__(256) void spmm_scatter_kernel(
    const int* __restrict__ rows, const int* __restrict__ cols,
    const float* __restrict__ vals, const float* __restrict__ src,
    float* __restrict__ dst, int nEdges)
{
    const long long total  = (long long)nEdges * OUT_CH;
    const long long stride = (long long)gridDim.x * blockDim.x;
    for (long long g = (long long)blockIdx.x * blockDim.x + threadIdx.x;
         g < total; g += stride) {
        int e = (int)(g >> 6);
        int c = (int)(g & 63);
        int r = rows[e];
        int s = cols[e];
        float v = vals[e] * src[(size_t)s * OUT_CH + c];
        atomicAdd(&dst[(size_t)r * OUT_CH + c], v);
    }
}

extern "C" void kernel_launch(void* const* d_in, const int* in_sizes, int n_in,
                              void* d_out, int out_size, void* d_ws, size_t ws_size,
                              hipStream_t stream)
{
    const int*   adj  = (const int*)d_in[0];    // [2, E] int32
    const float* vals = (const float*)d_in[1];  // [E]
    const float* feat = (const float*)d_in[2];  // [N, 256]
    const float* W    = (const float*)d_in[3];  // [256, 64]
    const float* bias = (const float*)d_in[4];  // [1, 64]

    const int E = in_sizes[1];
    const int n = in_sizes[2] / IN_CH;
    const int* rows = adj;       // destination rows
    const int* cols = adj + E;   // gather sources

    float* A   = (float*)d_ws;   // ping buffer (needs n*64*4 = 25.6 MB of ws)
    float* out = (float*)d_out;  // pong buffer doubles as final output
    const size_t nb = (size_t)n * OUT_CH * sizeof(float);

    // base = relu(feat @ W + bias) -> A
    dim3 ggrid((n + 63) / 64);
    gemm_relu_kernel<<<ggrid, 256, 0, stream>>>(feat, W, bias, A, n);

    const int sblocks = 8192;  // grid-stride over E*64 lanes

    // hop 1: A -> out
    hipMemsetAsync(out, 0, nb, stream);
    spmm_scatter_kernel<<<sblocks, 256, 0, stream>>>(rows, cols, vals, A, out, E);
    // hop 2: out -> A
    hipMemsetAsync(A, 0, nb, stream);
    spmm_scatter_kernel<<<sblocks, 256, 0, stream>>>(rows, cols, vals, out, A, E);
    // hop 3: A -> out   (final result lands in d_out)
    hipMemsetAsync(out, 0, nb, stream);
    spmm_scatter_kernel<<<sblocks, 256, 0, stream>>>(rows, cols, vals, A, out, E);
}

// Round 2
// 585.132 us; speedup vs baseline: 2.1072x; 2.1072x over previous
//
#include <hip/hip_runtime.h>

#define IN_CH 256
#define OUT_CH 64
#define SCAN_CHUNK 1024   // elements per scan block (256 threads x 4)

// ---------------------------------------------------------------------------
// Dense transform: out[n][64] = relu(feat[n][256] @ W[256][64] + bias[64])
// ---------------------------------------------------------------------------
__global__ __launch_bounds__(256) void gemm_relu_kernel(
    const float* __restrict__ feat, const float* __restrict__ W,
    const float* __restrict__ bias, float* __restrict__ out, int n)
{
    constexpr int BM = 64, BK = 64, PAD = 68;
    __shared__ float As[BM][PAD];
    __shared__ float Bs[BK][PAD];

    const int tid = threadIdx.x;
    const int tx = tid & 15;
    const int ty = tid >> 4;
    const int row0 = blockIdx.x * BM;

    float acc[4][4];
#pragma unroll
    for (int i = 0; i < 4; ++i)
#pragma unroll
        for (int j = 0; j < 4; ++j) acc[i][j] = 0.f;

    const float4* feat4 = (const float4*)feat;
    const float4* W4    = (const float4*)W;

    for (int k0 = 0; k0 < IN_CH; k0 += BK) {
#pragma unroll
        for (int i = 0; i < 4; ++i) {
            int li = tid + i * 256;
            int r  = li >> 4;
            int c4 = li & 15;
            int grow = row0 + r;
            float4 v = make_float4(0.f, 0.f, 0.f, 0.f);
            if (grow < n) v = feat4[(size_t)grow * (IN_CH / 4) + (k0 >> 2) + c4];
            *(float4*)&As[r][c4 * 4] = v;
            float4 w = W4[(size_t)(k0 + r) * (OUT_CH / 4) + c4];
            *(float4*)&Bs[r][c4 * 4] = w;
        }
        __syncthreads();

#pragma unroll
        for (int kk = 0; kk < BK; ++kk) {
            float4 b = *(const float4*)&Bs[kk][tx * 4];
#pragma unroll
            for (int i = 0; i < 4; ++i) {
                float a = As[ty * 4 + i][kk];
                acc[i][0] += a * b.x;
                acc[i][1] += a * b.y;
                acc[i][2] += a * b.z;
                acc[i][3] += a * b.w;
            }
        }
        __syncthreads();
    }

    float4 bv = ((const float4*)bias)[tx];
#pragma unroll
    for (int i = 0; i < 4; ++i) {
        int grow = row0 + ty * 4 + i;
        if (grow < n) {
            float4 o;
            o.x = fmaxf(acc[i][0] + bv.x, 0.f);
            o.y = fmaxf(acc[i][1] + bv.y, 0.f);
            o.z = fmaxf(acc[i][2] + bv.z, 0.f);
            o.w = fmaxf(acc[i][3] + bv.w, 0.f);
            *(float4*)&out[(size_t)grow * OUT_CH + tx * 4] = o;
        }
    }
}

// ---------------------------------------------------------------------------
// CSR build: histogram -> two-level exclusive scan -> cursor scatter
// ---------------------------------------------------------------------------
__global__ __launch_bounds__(256) void hist_kernel(
    const int* __restrict__ rows, int* __restrict__ cnt, int nEdges)
{
    int stride = gridDim.x * blockDim.x;
    for (int e = blockIdx.x * blockDim.x + threadIdx.x; e < nEdges; e += stride)
        atomicAdd(&cnt[rows[e]], 1);
}

__global__ __launch_bounds__(256) void block_sum_kernel(
    const int* __restrict__ cnt, int* __restrict__ blockSums, int n)
{
    __shared__ int ls[256];
    int t = threadIdx.x;
    int base = blockIdx.x * SCAN_CHUNK + t * 4;
    int s = 0;
#pragma unroll
    for (int j = 0; j < 4; ++j) {
        int i = base + j;
        if (i < n) s += cnt[i];
    }
    ls[t] = s;
    __syncthreads();
    for (int off = 128; off > 0; off >>= 1) {
        if (t < off) ls[t] += ls[t + off];
        __syncthreads();
    }
    if (t == 0) blockSums[blockIdx.x] = ls[0];
}

__global__ void scan_sums_kernel(int* __restrict__ blockSums, int nb,
                                 int* __restrict__ rowptr, int n, int total)
{
    // single thread: nb <= ~100, negligible
    int run = 0;
    for (int i = 0; i < nb; ++i) {
        int c = blockSums[i];
        blockSums[i] = run;
        run += c;
    }
    rowptr[n] = total;
}

__global__ __launch_bounds__(256) void scan_final_kernel(
    const int* __restrict__ cnt, const int* __restrict__ blockSums,
    int* __restrict__ rowptr, int* __restrict__ cursor, int n)
{
    __shared__ int ls[256];
    int t = threadIdx.x;
    int base = blockIdx.x * SCAN_CHUNK + t * 4;
    int v0 = (base + 0 < n) ? cnt[base + 0] : 0;
    int v1 = (base + 1 < n) ? cnt[base + 1] : 0;
    int v2 = (base + 2 < n) ? cnt[base + 2] : 0;
    int v3 = (base + 3 < n) ? cnt[base + 3] : 0;
    ls[t] = v0 + v1 + v2 + v3;
    __syncthreads();
    // Hillis-Steele inclusive scan over 256 thread-sums
    for (int off = 1; off < 256; off <<= 1) {
        int x = (t >= off) ? ls[t - off] : 0;
        __syncthreads();
        ls[t] += x;
        __syncthreads();
    }
    int prefix = blockSums[blockIdx.x] + (t ? ls[t - 1] : 0);
    int e0 = prefix;
    int e1 = e0 + v0;
    int e2 = e1 + v1;
    int e3 = e2 + v2;
    if (base + 0 < n) { rowptr[base + 0] = e0; cursor[base + 0] = e0; }
    if (base + 1 < n) { rowptr[base + 1] = e1; cursor[base + 1] = e1; }
    if (base + 2 < n) { rowptr[base + 2] = e2; cursor[base + 2] = e2; }
    if (base + 3 < n) { rowptr[base + 3] = e3; cursor[base + 3] = e3; }
}

__global__ __launch_bounds__(256) void scatter_edges_kernel(
    const int* __restrict__ rows, const int* __restrict__ cols,
    const float* __restrict__ vals, int* __restrict__ cursor,
    int* __restrict__ scol, float* __restrict__ sval, int nEdges)
{
    int stride = gridDim.x * blockDim.x;
    for (int e = blockIdx.x * blockDim.x + threadIdx.x; e < nEdges; e += stride) {
        int r = rows[e];
        int pos = atomicAdd(&cursor[r], 1);
        scol[pos] = cols[e];
        sval[pos] = vals[e];
    }
}

// ---------------------------------------------------------------------------
// CSR SpMM hop: one wave per row, lane = output channel.
// cols/vals fetched 64-at-a-time by lanes, broadcast via shfl; gather rows
// are 256 B coalesced; accumulate in 4 independent regs; no atomics.
// ---------------------------------------------------------------------------
__global__ __launch_bounds__(256) void spmm_csr_kernel(
    const int* __restrict__ rowptr, const int* __restrict__ scol,
    const float* __restrict__ sval, const float* __restrict__ src,
    float* __restrict__ dst, int n)
{
    const int row  = blockIdx.x * 4 + (threadIdx.x >> 6);
    const int lane = threadIdx.x & 63;
    if (row >= n) return;

    const int beg = rowptr[row];
    const int end = rowptr[row + 1];

    float a0 = 0.f, a1 = 0.f, a2 = 0.f, a3 = 0.f;

    for (int b = beg; b < end; b += 64) {
        const int m = min(64, end - b);
        int   c = 0;
        float v = 0.f;
        if (lane < m) { c = scol[b + lane]; v = sval[b + lane]; }

        int j = 0;
        for (; j + 3 < m; j += 4) {
            int   c0 = __shfl(c, j + 0); float v0 = __shfl(v, j + 0);
            int   c1 = __shfl(c, j + 1); float v1 = __shfl(v, j + 1);
            int   c2 = __shfl(c, j + 2); float v2 = __shfl(v, j + 2);
            int   c3 = __shfl(c, j + 3); float v3 = __shfl(v, j + 3);
            float s0 = src[((size_t)c0 << 6) + lane];
            float s1 = src[((size_t)c1 << 6) + lane];
            float s2 = src[((size_t)c2 << 6) + lane];
            float s3 = src[((size_t)c3 << 6) + lane];
            a0 += v0 * s0;
            a1 += v1 * s1;
            a2 += v2 * s2;
            a3 += v3 * s3;
        }
        for (; j < m; ++j) {
            int   cj = __shfl(c, j);
            float vj = __shfl(v, j);
            a0 += vj * src[((size_t)cj << 6) + lane];
        }
    }

    dst[((size_t)row << 6) + lane] = (a0 + a1) + (a2 + a3);
}

// ---------------------------------------------------------------------------
extern "C" void kernel_launch(void* const* d_in, const int* in_sizes, int n_in,
                              void* d_out, int out_size, void* d_ws, size_t ws_size,
                              hipStream_t stream)
{
    const int*   adj  = (const int*)d_in[0];    // [2, E] int32
    const float* vals = (const float*)d_in[1];  // [E]
    const float* feat = (const float*)d_in[2];  // [N, 256]
    const float* W    = (const float*)d_in[3];  // [256, 64]
    const float* bias = (const float*)d_in[4];  // [1, 64]

    const int E = in_sizes[1];
    const int n = in_sizes[2] / IN_CH;
    const int* rows = adj;       // destination rows
    const int* cols = adj + E;   // gather sources

    // ---- workspace layout (256 B aligned regions) ----
    char* ws = (char*)d_ws;
    size_t off = 0;
    auto alloc = [&](size_t bytes) {
        void* p = ws + off;
        off += (bytes + 255) & ~(size_t)255;
        return p;
    };
    float* A         = (float*)alloc((size_t)n * OUT_CH * sizeof(float)); // ping
    int*   rowptr    = (int*)  alloc((size_t)(n + 1) * sizeof(int));
    int*   cursor    = (int*)  alloc((size_t)n * sizeof(int));            // counts, then cursors
    int*   scol      = (int*)  alloc((size_t)E * sizeof(int));
    float* sval      = (float*)alloc((size_t)E * sizeof(float));
    int*   blockSums = (int*)  alloc(4096 * sizeof(int));

    float* out = (float*)d_out;

    // ---- build CSR ----
    hipMemsetAsync(cursor, 0, (size_t)n * sizeof(int), stream);
    hist_kernel<<<2048, 256, 0, stream>>>(rows, cursor, E);

    const int nb = (n + SCAN_CHUNK - 1) / SCAN_CHUNK;
    block_sum_kernel<<<nb, 256, 0, stream>>>(cursor, blockSums, n);
    scan_sums_kernel<<<1, 1, 0, stream>>>(blockSums, nb, rowptr, n, E);
    scan_final_kernel<<<nb, 256, 0, stream>>>(cursor, blockSums, rowptr, cursor, n);
    scatter_edges_kernel<<<2048, 256, 0, stream>>>(rows, cols, vals, cursor, scol, sval, E);

    // ---- dense transform ----
    gemm_relu_kernel<<<(n + 63) / 64, 256, 0, stream>>>(feat, W, bias, A, n);

    // ---- 3 SpMM hops (no memsets needed: every row written once) ----
    const int hblocks = (n + 3) / 4;
    spmm_csr_kernel<<<hblocks, 256, 0, stream>>>(rowptr, scol, sval, A, out, n);
    spmm_csr_kernel<<<hblocks, 256, 0, stream>>>(rowptr, scol, sval, out, A, n);
    spmm_csr_kernel<<<hblocks, 256, 0, stream>>>(rowptr, scol, sval, A, out, n);
}

// Round 3
// 583.824 us; speedup vs baseline: 2.1119x; 1.0022x over previous
//
#include <hip/hip_runtime.h>

#define IN_CH 256
#define OUT_CH 64
#define SCAN_CHUNK 1024   // elements per scan block (256 threads x 4)

// ---------------------------------------------------------------------------
// Dense transform: out[n][64] = relu(feat[n][256] @ W[256][64] + bias[64])
// ---------------------------------------------------------------------------
__global__ __launch_bounds__(256) void gemm_relu_kernel(
    const float* __restrict__ feat, const float* __restrict__ W,
    const float* __restrict__ bias, float* __restrict__ out, int n)
{
    constexpr int BM = 64, BK = 64, PAD = 68;
    __shared__ float As[BM][PAD];
    __shared__ float Bs[BK][PAD];

    const int tid = threadIdx.x;
    const int tx = tid & 15;
    const int ty = tid >> 4;
    const int row0 = blockIdx.x * BM;

    float acc[4][4];
#pragma unroll
    for (int i = 0; i < 4; ++i)
#pragma unroll
        for (int j = 0; j < 4; ++j) acc[i][j] = 0.f;

    const float4* feat4 = (const float4*)feat;
    const float4* W4    = (const float4*)W;

    for (int k0 = 0; k0 < IN_CH; k0 += BK) {
#pragma unroll
        for (int i = 0; i < 4; ++i) {
            int li = tid + i * 256;
            int r  = li >> 4;
            int c4 = li & 15;
            int grow = row0 + r;
            float4 v = make_float4(0.f, 0.f, 0.f, 0.f);
            if (grow < n) v = feat4[(size_t)grow * (IN_CH / 4) + (k0 >> 2) + c4];
            *(float4*)&As[r][c4 * 4] = v;
            float4 w = W4[(size_t)(k0 + r) * (OUT_CH / 4) + c4];
            *(float4*)&Bs[r][c4 * 4] = w;
        }
        __syncthreads();

#pragma unroll
        for (int kk = 0; kk < BK; ++kk) {
            float4 b = *(const float4*)&Bs[kk][tx * 4];
#pragma unroll
            for (int i = 0; i < 4; ++i) {
                float a = As[ty * 4 + i][kk];
                acc[i][0] += a * b.x;
                acc[i][1] += a * b.y;
                acc[i][2] += a * b.z;
                acc[i][3] += a * b.w;
            }
        }
        __syncthreads();
    }

    float4 bv = ((const float4*)bias)[tx];
#pragma unroll
    for (int i = 0; i < 4; ++i) {
        int grow = row0 + ty * 4 + i;
        if (grow < n) {
            float4 o;
            o.x = fmaxf(acc[i][0] + bv.x, 0.f);
            o.y = fmaxf(acc[i][1] + bv.y, 0.f);
            o.z = fmaxf(acc[i][2] + bv.z, 0.f);
            o.w = fmaxf(acc[i][3] + bv.w, 0.f);
            *(float4*)&out[(size_t)grow * OUT_CH + tx * 4] = o;
        }
    }
}

// ---------------------------------------------------------------------------
// CSR build: histogram -> two-level exclusive scan -> cursor scatter
// ---------------------------------------------------------------------------
__global__ __launch_bounds__(256) void hist_kernel(
    const int* __restrict__ rows, int* __restrict__ cnt, int nEdges)
{
    int stride = gridDim.x * blockDim.x;
    for (int e = blockIdx.x * blockDim.x + threadIdx.x; e < nEdges; e += stride)
        atomicAdd(&cnt[rows[e]], 1);
}

__global__ __launch_bounds__(256) void block_sum_kernel(
    const int* __restrict__ cnt, int* __restrict__ blockSums, int n)
{
    __shared__ int ls[256];
    int t = threadIdx.x;
    int base = blockIdx.x * SCAN_CHUNK + t * 4;
    int s = 0;
#pragma unroll
    for (int j = 0; j < 4; ++j) {
        int i = base + j;
        if (i < n) s += cnt[i];
    }
    ls[t] = s;
    __syncthreads();
    for (int off = 128; off > 0; off >>= 1) {
        if (t < off) ls[t] += ls[t + off];
        __syncthreads();
    }
    if (t == 0) blockSums[blockIdx.x] = ls[0];
}

__global__ void scan_sums_kernel(int* __restrict__ blockSums, int nb,
                                 int* __restrict__ rowptr, int n, int total)
{
    int run = 0;
    for (int i = 0; i < nb; ++i) {
        int c = blockSums[i];
        blockSums[i] = run;
        run += c;
    }
    rowptr[n] = total;
}

__global__ __launch_bounds__(256) void scan_final_kernel(
    const int* __restrict__ cnt, const int* __restrict__ blockSums,
    int* __restrict__ rowptr, int* __restrict__ cursor, int n)
{
    __shared__ int ls[256];
    int t = threadIdx.x;
    int base = blockIdx.x * SCAN_CHUNK + t * 4;
    int v0 = (base + 0 < n) ? cnt[base + 0] : 0;
    int v1 = (base + 1 < n) ? cnt[base + 1] : 0;
    int v2 = (base + 2 < n) ? cnt[base + 2] : 0;
    int v3 = (base + 3 < n) ? cnt[base + 3] : 0;
    ls[t] = v0 + v1 + v2 + v3;
    __syncthreads();
    for (int off = 1; off < 256; off <<= 1) {
        int x = (t >= off) ? ls[t - off] : 0;
        __syncthreads();
        ls[t] += x;
        __syncthreads();
    }
    int prefix = blockSums[blockIdx.x] + (t ? ls[t - 1] : 0);
    int e0 = prefix;
    int e1 = e0 + v0;
    int e2 = e1 + v1;
    int e3 = e2 + v2;
    if (base + 0 < n) { rowptr[base + 0] = e0; cursor[base + 0] = e0; }
    if (base + 1 < n) { rowptr[base + 1] = e1; cursor[base + 1] = e1; }
    if (base + 2 < n) { rowptr[base + 2] = e2; cursor[base + 2] = e2; }
    if (base + 3 < n) { rowptr[base + 3] = e3; cursor[base + 3] = e3; }
}

// Pack (col, val) into one int2 so the random scatter is a single 8 B store
// per edge (one 64 B line touch instead of two).
__global__ __launch_bounds__(256) void scatter_edges_kernel(
    const int* __restrict__ rows, const int* __restrict__ cols,
    const float* __restrict__ vals, int* __restrict__ cursor,
    int2* __restrict__ spack, int nEdges)
{
    int stride = gridDim.x * blockDim.x;
    for (int e = blockIdx.x * blockDim.x + threadIdx.x; e < nEdges; e += stride) {
        int r = rows[e];
        int pos = atomicAdd(&cursor[r], 1);
        spack[pos] = make_int2(cols[e], __float_as_int(vals[e]));
    }
}

// ---------------------------------------------------------------------------
// CSR SpMM hop: one wave per row, quarter-wave per edge, lane = float4 group.
// 8 edges in flight per iteration, zero inner-loop shfls, 2-step xor-reduce
// epilogue, 256 B coalesced stores. No atomics, no dst memset needed.
// ---------------------------------------------------------------------------
__global__ __launch_bounds__(256) void spmm_csr_kernel(
    const int* __restrict__ rowptr, const int2* __restrict__ spack,
    const float* __restrict__ src, float* __restrict__ dst, int n)
{
    const int row  = blockIdx.x * 4 + (threadIdx.x >> 6);
    const int lane = threadIdx.x & 63;
    if (row >= n) return;

    const int beg = rowptr[row];
    const int end = rowptr[row + 1];
    const int sub = lane >> 4;        // which edge of the group of 4
    const int ch  = (lane & 15) * 4;  // channel offset of this lane's float4

    float4 acc = make_float4(0.f, 0.f, 0.f, 0.f);

    for (int b = beg; b < end; b += 8) {
        int e0 = b + sub;
        int e1 = b + 4 + sub;
        float v0 = 0.f, v1 = 0.f;
        float4 s0 = make_float4(0.f, 0.f, 0.f, 0.f);
        float4 s1 = make_float4(0.f, 0.f, 0.f, 0.f);
        if (e0 < end) {
            int2 p = spack[e0];
            v0 = __int_as_float(p.y);
            s0 = *(const float4*)(src + ((size_t)p.x << 6) + ch);
        }
        if (e1 < end) {
            int2 p = spack[e1];
            v1 = __int_as_float(p.y);
            s1 = *(const float4*)(src + ((size_t)p.x << 6) + ch);
        }
        acc.x = fmaf(v0, s0.x, acc.x);
        acc.y = fmaf(v0, s0.y, acc.y);
        acc.z = fmaf(v0, s0.z, acc.z);
        acc.w = fmaf(v0, s0.w, acc.w);
        acc.x = fmaf(v1, s1.x, acc.x);
        acc.y = fmaf(v1, s1.y, acc.y);
        acc.z = fmaf(v1, s1.z, acc.z);
        acc.w = fmaf(v1, s1.w, acc.w);
    }

    // reduce across the 4 quarter-waves (sub groups)
#pragma unroll
    for (int mask = 16; mask <= 32; mask <<= 1) {
        acc.x += __shfl_xor(acc.x, mask);
        acc.y += __shfl_xor(acc.y, mask);
        acc.z += __shfl_xor(acc.z, mask);
        acc.w += __shfl_xor(acc.w, mask);
    }

    if (lane < 16)
        *(float4*)(dst + ((size_t)row << 6) + ch) = acc;
}

// ---------------------------------------------------------------------------
extern "C" void kernel_launch(void* const* d_in, const int* in_sizes, int n_in,
                              void* d_out, int out_size, void* d_ws, size_t ws_size,
                              hipStream_t stream)
{
    const int*   adj  = (const int*)d_in[0];    // [2, E] int32
    const float* vals = (const float*)d_in[1];  // [E]
    const float* feat = (const float*)d_in[2];  // [N, 256]
    const float* W    = (const float*)d_in[3];  // [256, 64]
    const float* bias = (const float*)d_in[4];  // [1, 64]

    const int E = in_sizes[1];
    const int n = in_sizes[2] / IN_CH;
    const int* rows = adj;       // destination rows
    const int* cols = adj + E;   // gather sources

    // ---- workspace layout (256 B aligned regions) ----
    char* ws = (char*)d_ws;
    size_t off = 0;
    auto alloc = [&](size_t bytes) {
        void* p = ws + off;
        off += (bytes + 255) & ~(size_t)255;
        return p;
    };
    float* A         = (float*)alloc((size_t)n * OUT_CH * sizeof(float)); // ping
    int*   rowptr    = (int*)  alloc((size_t)(n + 1) * sizeof(int));
    int*   cursor    = (int*)  alloc((size_t)n * sizeof(int));
    int2*  spack     = (int2*) alloc((size_t)E * sizeof(int2));
    int*   blockSums = (int*)  alloc(4096 * sizeof(int));

    float* out = (float*)d_out;

    // ---- build CSR ----
    hipMemsetAsync(cursor, 0, (size_t)n * sizeof(int), stream);
    hist_kernel<<<2048, 256, 0, stream>>>(rows, cursor, E);

    const int nb = (n + SCAN_CHUNK - 1) / SCAN_CHUNK;
    block_sum_kernel<<<nb, 256, 0, stream>>>(cursor, blockSums, n);
    scan_sums_kernel<<<1, 1, 0, stream>>>(blockSums, nb, rowptr, n, E);
    scan_final_kernel<<<nb, 256, 0, stream>>>(cursor, blockSums, rowptr, cursor, n);
    scatter_edges_kernel<<<2048, 256, 0, stream>>>(rows, cols, vals, cursor, spack, E);

    // ---- dense transform ----
    gemm_relu_kernel<<<(n + 63) / 64, 256, 0, stream>>>(feat, W, bias, A, n);

    // ---- 3 SpMM hops ----
    const int hblocks = (n + 3) / 4;
    spmm_csr_kernel<<<hblocks, 256, 0, stream>>>(rowptr, spack, A, out, n);
    spmm_csr_kernel<<<hblocks, 256, 0, stream>>>(rowptr, spack, out, A, n);
    spmm_csr_kernel<<<hblocks, 256, 0, stream>>>(rowptr, spack, A, out, n);
}

// Round 4
// 563.980 us; speedup vs baseline: 2.1862x; 1.0352x over previous
//
#include <hip/hip_runtime.h>

#define IN_CH 256
#define OUT_CH 64
#define SCAN_CHUNK 1024   // elements per scan block (256 threads x 4)

// ---- bf16 helpers (RNE), manual to keep codegen tight ----
__device__ __forceinline__ unsigned short f2bf(float f) {
    unsigned u = __float_as_uint(f);
    u += 0x7fff + ((u >> 16) & 1);
    return (unsigned short)(u >> 16);
}
__device__ __forceinline__ float bf2f(unsigned short h) {
    return __uint_as_float((unsigned)h << 16);
}

// ---------------------------------------------------------------------------
// Dense transform: B0[n][64] = bf16(relu(feat[n][256] @ W[256][64] + bias))
// ---------------------------------------------------------------------------
__global__ __launch_bounds__(256) void gemm_relu_kernel(
    const float* __restrict__ feat, const float* __restrict__ W,
    const float* __restrict__ bias, unsigned short* __restrict__ out, int n)
{
    constexpr int BM = 64, BK = 64, PAD = 68;
    __shared__ float As[BM][PAD];
    __shared__ float Bs[BK][PAD];

    const int tid = threadIdx.x;
    const int tx = tid & 15;
    const int ty = tid >> 4;
    const int row0 = blockIdx.x * BM;

    float acc[4][4];
#pragma unroll
    for (int i = 0; i < 4; ++i)
#pragma unroll
        for (int j = 0; j < 4; ++j) acc[i][j] = 0.f;

    const float4* feat4 = (const float4*)feat;
    const float4* W4    = (const float4*)W;

    for (int k0 = 0; k0 < IN_CH; k0 += BK) {
#pragma unroll
        for (int i = 0; i < 4; ++i) {
            int li = tid + i * 256;
            int r  = li >> 4;
            int c4 = li & 15;
            int grow = row0 + r;
            float4 v = make_float4(0.f, 0.f, 0.f, 0.f);
            if (grow < n) v = feat4[(size_t)grow * (IN_CH / 4) + (k0 >> 2) + c4];
            *(float4*)&As[r][c4 * 4] = v;
            float4 w = W4[(size_t)(k0 + r) * (OUT_CH / 4) + c4];
            *(float4*)&Bs[r][c4 * 4] = w;
        }
        __syncthreads();

#pragma unroll
        for (int kk = 0; kk < BK; ++kk) {
            float4 b = *(const float4*)&Bs[kk][tx * 4];
#pragma unroll
            for (int i = 0; i < 4; ++i) {
                float a = As[ty * 4 + i][kk];
                acc[i][0] += a * b.x;
                acc[i][1] += a * b.y;
                acc[i][2] += a * b.z;
                acc[i][3] += a * b.w;
            }
        }
        __syncthreads();
    }

    float4 bv = ((const float4*)bias)[tx];
#pragma unroll
    for (int i = 0; i < 4; ++i) {
        int grow = row0 + ty * 4 + i;
        if (grow < n) {
            ushort4 o;
            o.x = f2bf(fmaxf(acc[i][0] + bv.x, 0.f));
            o.y = f2bf(fmaxf(acc[i][1] + bv.y, 0.f));
            o.z = f2bf(fmaxf(acc[i][2] + bv.z, 0.f));
            o.w = f2bf(fmaxf(acc[i][3] + bv.w, 0.f));
            *(ushort4*)&out[(size_t)grow * OUT_CH + tx * 4] = o;
        }
    }
}

// ---------------------------------------------------------------------------
// CSR build: histogram -> two-level exclusive scan -> cursor scatter
// ---------------------------------------------------------------------------
__global__ __launch_bounds__(256) void hist_kernel(
    const int* __restrict__ rows, int* __restrict__ cnt, int nEdges)
{
    int t = blockIdx.x * blockDim.x + threadIdx.x;
    int base = t * 4;
    if (base + 3 < nEdges) {
        int4 r4 = *(const int4*)(rows + base);
        atomicAdd(&cnt[r4.x], 1);
        atomicAdd(&cnt[r4.y], 1);
        atomicAdd(&cnt[r4.z], 1);
        atomicAdd(&cnt[r4.w], 1);
    } else {
        for (int e = base; e < nEdges; ++e) atomicAdd(&cnt[rows[e]], 1);
    }
}

__global__ __launch_bounds__(256) void block_sum_kernel(
    const int* __restrict__ cnt, int* __restrict__ blockSums, int n)
{
    __shared__ int ls[256];
    int t = threadIdx.x;
    int base = blockIdx.x * SCAN_CHUNK + t * 4;
    int s = 0;
#pragma unroll
    for (int j = 0; j < 4; ++j) {
        int i = base + j;
        if (i < n) s += cnt[i];
    }
    ls[t] = s;
    __syncthreads();
    for (int off = 128; off > 0; off >>= 1) {
        if (t < off) ls[t] += ls[t + off];
        __syncthreads();
    }
    if (t == 0) blockSums[blockIdx.x] = ls[0];
}

__global__ void scan_sums_kernel(int* __restrict__ blockSums, int nb,
                                 int* __restrict__ rowptr, int n, int total)
{
    int run = 0;
    for (int i = 0; i < nb; ++i) {
        int c = blockSums[i];
        blockSums[i] = run;
        run += c;
    }
    rowptr[n] = total;
}

__global__ __launch_bounds__(256) void scan_final_kernel(
    const int* __restrict__ cnt, const int* __restrict__ blockSums,
    int* __restrict__ rowptr, int* __restrict__ cursor, int n)
{
    __shared__ int ls[256];
    int t = threadIdx.x;
    int base = blockIdx.x * SCAN_CHUNK + t * 4;
    int v0 = (base + 0 < n) ? cnt[base + 0] : 0;
    int v1 = (base + 1 < n) ? cnt[base + 1] : 0;
    int v2 = (base + 2 < n) ? cnt[base + 2] : 0;
    int v3 = (base + 3 < n) ? cnt[base + 3] : 0;
    ls[t] = v0 + v1 + v2 + v3;
    __syncthreads();
    for (int off = 1; off < 256; off <<= 1) {
        int x = (t >= off) ? ls[t - off] : 0;
        __syncthreads();
        ls[t] += x;
        __syncthreads();
    }
    int prefix = blockSums[blockIdx.x] + (t ? ls[t - 1] : 0);
    int e0 = prefix;
    int e1 = e0 + v0;
    int e2 = e1 + v1;
    int e3 = e2 + v2;
    if (base + 0 < n) { rowptr[base + 0] = e0; cursor[base + 0] = e0; }
    if (base + 1 < n) { rowptr[base + 1] = e1; cursor[base + 1] = e1; }
    if (base + 2 < n) { rowptr[base + 2] = e2; cursor[base + 2] = e2; }
    if (base + 3 < n) { rowptr[base + 3] = e3; cursor[base + 3] = e3; }
}

// 4 edges per thread, phase-separated: vector edge loads, then 4 independent
// atomics in flight, then 4 packed 8 B stores. MLP x4 vs the grid-stride loop.
__global__ __launch_bounds__(256) void scatter_edges_kernel(
    const int* __restrict__ rows, const int* __restrict__ cols,
    const float* __restrict__ vals, int* __restrict__ cursor,
    int2* __restrict__ spack, int nEdges)
{
    int t = blockIdx.x * blockDim.x + threadIdx.x;
    int base = t * 4;
    if (base + 3 < nEdges) {
        int4   r4 = *(const int4*)(rows + base);
        int4   c4 = *(const int4*)(cols + base);
        float4 v4 = *(const float4*)(vals + base);
        int p0 = atomicAdd(&cursor[r4.x], 1);
        int p1 = atomicAdd(&cursor[r4.y], 1);
        int p2 = atomicAdd(&cursor[r4.z], 1);
        int p3 = atomicAdd(&cursor[r4.w], 1);
        spack[p0] = make_int2(c4.x, __float_as_int(v4.x));
        spack[p1] = make_int2(c4.y, __float_as_int(v4.y));
        spack[p2] = make_int2(c4.z, __float_as_int(v4.z));
        spack[p3] = make_int2(c4.w, __float_as_int(v4.w));
    } else {
        for (int e = base; e < nEdges; ++e) {
            int pos = atomicAdd(&cursor[rows[e]], 1);
            spack[pos] = make_int2(cols[e], __float_as_int(vals[e]));
        }
    }
}

// ---------------------------------------------------------------------------
// CSR SpMM hop, bf16 src: one wave per row, quarter-wave per edge, lane =
// 4-channel group (8 B gather, 128 B per edge). fp32 accumulate, 2-step
// xor-reduce, coalesced store (bf16 for intermediate hops, fp32 for final).
// ---------------------------------------------------------------------------
template<bool DST_F32>
__global__ __launch_bounds__(256) void spmm_csr_kernel(
    const int* __restrict__ rowptr, const int2* __restrict__ spack,
    const unsigned short* __restrict__ src, void* __restrict__ dstv, int n)
{
    const int row  = blockIdx.x * 4 + (threadIdx.x >> 6);
    const int lane = threadIdx.x & 63;
    if (row >= n) return;

    const int beg = rowptr[row];
    const int end = rowptr[row + 1];
    const int sub = lane >> 4;        // which edge of the group of 4
    const int ch  = (lane & 15) * 4;  // channel offset of this lane's group

    float4 acc = make_float4(0.f, 0.f, 0.f, 0.f);

    for (int b = beg; b < end; b += 8) {
        int e0 = b + sub;
        int e1 = b + 4 + sub;
        float v0 = 0.f, v1 = 0.f;
        ushort4 s0 = make_ushort4(0, 0, 0, 0);
        ushort4 s1 = make_ushort4(0, 0, 0, 0);
        if (e0 < end) {
            int2 p = spack[e0];
            v0 = __int_as_float(p.y);
            s0 = *(const ushort4*)(src + ((size_t)p.x << 6) + ch);
        }
        if (e1 < end) {
            int2 p = spack[e1];
            v1 = __int_as_float(p.y);
            s1 = *(const ushort4*)(src + ((size_t)p.x << 6) + ch);
        }
        acc.x = fmaf(v0, bf2f(s0.x), acc.x);
        acc.y = fmaf(v0, bf2f(s0.y), acc.y);
        acc.z = fmaf(v0, bf2f(s0.z), acc.z);
        acc.w = fmaf(v0, bf2f(s0.w), acc.w);
        acc.x = fmaf(v1, bf2f(s1.x), acc.x);
        acc.y = fmaf(v1, bf2f(s1.y), acc.y);
        acc.z = fmaf(v1, bf2f(s1.z), acc.z);
        acc.w = fmaf(v1, bf2f(s1.w), acc.w);
    }

#pragma unroll
    for (int mask = 16; mask <= 32; mask <<= 1) {
        acc.x += __shfl_xor(acc.x, mask);
        acc.y += __shfl_xor(acc.y, mask);
        acc.z += __shfl_xor(acc.z, mask);
        acc.w += __shfl_xor(acc.w, mask);
    }

    if (lane < 16) {
        if constexpr (DST_F32) {
            *(float4*)((float*)dstv + ((size_t)row << 6) + ch) = acc;
        } else {
            ushort4 o;
            o.x = f2bf(acc.x);
            o.y = f2bf(acc.y);
            o.z = f2bf(acc.z);
            o.w = f2bf(acc.w);
            *(ushort4*)((unsigned short*)dstv + ((size_t)row << 6) + ch) = o;
        }
    }
}

// ---------------------------------------------------------------------------
extern "C" void kernel_launch(void* const* d_in, const int* in_sizes, int n_in,
                              void* d_out, int out_size, void* d_ws, size_t ws_size,
                              hipStream_t stream)
{
    const int*   adj  = (const int*)d_in[0];    // [2, E] int32
    const float* vals = (const float*)d_in[1];  // [E]
    const float* feat = (const float*)d_in[2];  // [N, 256]
    const float* W    = (const float*)d_in[3];  // [256, 64]
    const float* bias = (const float*)d_in[4];  // [1, 64]

    const int E = in_sizes[1];
    const int n = in_sizes[2] / IN_CH;
    const int* rows = adj;       // destination rows
    const int* cols = adj + E;   // gather sources

    // ---- workspace layout (256 B aligned regions) ----
    char* ws = (char*)d_ws;
    size_t off = 0;
    auto alloc = [&](size_t bytes) {
        void* p = ws + off;
        off += (bytes + 255) & ~(size_t)255;
        return p;
    };
    unsigned short* B0 = (unsigned short*)alloc((size_t)n * OUT_CH * sizeof(unsigned short));
    unsigned short* B1 = (unsigned short*)alloc((size_t)n * OUT_CH * sizeof(unsigned short));
    int*   rowptr    = (int*)  alloc((size_t)(n + 1) * sizeof(int));
    int*   cursor    = (int*)  alloc((size_t)n * sizeof(int));
    int2*  spack     = (int2*) alloc((size_t)E * sizeof(int2));
    int*   blockSums = (int*)  alloc(4096 * sizeof(int));

    float* out = (float*)d_out;

    // ---- build CSR ----
    hipMemsetAsync(cursor, 0, (size_t)n * sizeof(int), stream);
    const int eblocks = (E / 4 + 255) / 256;
    hist_kernel<<<eblocks, 256, 0, stream>>>(rows, cursor, E);

    const int nb = (n + SCAN_CHUNK - 1) / SCAN_CHUNK;
    block_sum_kernel<<<nb, 256, 0, stream>>>(cursor, blockSums, n);
    scan_sums_kernel<<<1, 1, 0, stream>>>(blockSums, nb, rowptr, n, E);
    scan_final_kernel<<<nb, 256, 0, stream>>>(cursor, blockSums, rowptr, cursor, n);
    scatter_edges_kernel<<<eblocks, 256, 0, stream>>>(rows, cols, vals, cursor, spack, E);

    // ---- dense transform (bf16 output) ----
    gemm_relu_kernel<<<(n + 63) / 64, 256, 0, stream>>>(feat, W, bias, B0, n);

    // ---- 3 SpMM hops: B0 -> B1 -> B0 -> out(fp32) ----
    const int hblocks = (n + 3) / 4;
    spmm_csr_kernel<false><<<hblocks, 256, 0, stream>>>(rowptr, spack, B0, B1, n);
    spmm_csr_kernel<false><<<hblocks, 256, 0, stream>>>(rowptr, spack, B1, B0, n);
    spmm_csr_kernel<true><<<hblocks, 256, 0, stream>>>(rowptr, spack, B0, out, n);
}

// Round 5
// 486.413 us; speedup vs baseline: 2.5348x; 1.1595x over previous
//
#include <hip/hip_runtime.h>

#define IN_CH 256
#define OUT_CH 64
#define SCAN_CHUNK 1024   // elements per scan block (256 threads x 4)
#define NGROUP 8          // one group per XCD (blockIdx & 7 round-robin)

// ---- bf16 helpers (RNE) ----
__device__ __forceinline__ unsigned short f2bf(float f) {
    unsigned u = __float_as_uint(f);
    u += 0x7fff + ((u >> 16) & 1);
    return (unsigned short)(u >> 16);
}
__device__ __forceinline__ float bf2f(unsigned short h) {
    return __uint_as_float((unsigned)h << 16);
}

// ---------------------------------------------------------------------------
// Dense transform: B0[n][64] = bf16(relu(feat[n][256] @ W[256][64] + bias))
// ---------------------------------------------------------------------------
__global__ __launch_bounds__(256) void gemm_relu_kernel(
    const float* __restrict__ feat, const float* __restrict__ W,
    const float* __restrict__ bias, unsigned short* __restrict__ out, int n)
{
    constexpr int BM = 64, BK = 64, PAD = 68;
    __shared__ float As[BM][PAD];
    __shared__ float Bs[BK][PAD];

    const int tid = threadIdx.x;
    const int tx = tid & 15;
    const int ty = tid >> 4;
    const int row0 = blockIdx.x * BM;

    float acc[4][4];
#pragma unroll
    for (int i = 0; i < 4; ++i)
#pragma unroll
        for (int j = 0; j < 4; ++j) acc[i][j] = 0.f;

    const float4* feat4 = (const float4*)feat;
    const float4* W4    = (const float4*)W;

    for (int k0 = 0; k0 < IN_CH; k0 += BK) {
#pragma unroll
        for (int i = 0; i < 4; ++i) {
            int li = tid + i * 256;
            int r  = li >> 4;
            int c4 = li & 15;
            int grow = row0 + r;
            float4 v = make_float4(0.f, 0.f, 0.f, 0.f);
            if (grow < n) v = feat4[(size_t)grow * (IN_CH / 4) + (k0 >> 2) + c4];
            *(float4*)&As[r][c4 * 4] = v;
            float4 w = W4[(size_t)(k0 + r) * (OUT_CH / 4) + c4];
            *(float4*)&Bs[r][c4 * 4] = w;
        }
        __syncthreads();

#pragma unroll
        for (int kk = 0; kk < BK; ++kk) {
            float4 b = *(const float4*)&Bs[kk][tx * 4];
#pragma unroll
            for (int i = 0; i < 4; ++i) {
                float a = As[ty * 4 + i][kk];
                acc[i][0] += a * b.x;
                acc[i][1] += a * b.y;
                acc[i][2] += a * b.z;
                acc[i][3] += a * b.w;
            }
        }
        __syncthreads();
    }

    float4 bv = ((const float4*)bias)[tx];
#pragma unroll
    for (int i = 0; i < 4; ++i) {
        int grow = row0 + ty * 4 + i;
        if (grow < n) {
            ushort4 o;
            o.x = f2bf(fmaxf(acc[i][0] + bv.x, 0.f));
            o.y = f2bf(fmaxf(acc[i][1] + bv.y, 0.f));
            o.z = f2bf(fmaxf(acc[i][2] + bv.z, 0.f));
            o.w = f2bf(fmaxf(acc[i][3] + bv.w, 0.f));
            *(ushort4*)&out[(size_t)grow * OUT_CH + tx * 4] = o;
        }
    }
}

// ---------------------------------------------------------------------------
// CSR build, XCD-localized: group g = blockIdx & 7 handles rows in
// [g*rpg, (g+1)*rpg). Every group streams all edges (L3 broadcast) but its
// atomics and scatter stores stay inside its own L2 slice -> full-line
// writeback merging instead of 8x-amplified partial lines.
// ---------------------------------------------------------------------------
__global__ __launch_bounds__(256) void hist_kernel(
    const int* __restrict__ rows, int* __restrict__ cnt, int nEdges, int rpg)
{
    const int g     = blockIdx.x & (NGROUP - 1);
    const int blkIn = blockIdx.x >> 3;
    const int nBlk  = gridDim.x >> 3;
    const int lo = g * rpg, hi = lo + rpg;
    const int stride = nBlk * blockDim.x;
    for (int e = blkIn * blockDim.x + threadIdx.x; e < nEdges; e += stride) {
        int r = rows[e];
        if (r >= lo && r < hi) atomicAdd(&cnt[r], 1);
    }
}

__global__ __launch_bounds__(256) void block_sum_kernel(
    const int* __restrict__ cnt, int* __restrict__ blockSums, int n)
{
    __shared__ int ls[256];
    int t = threadIdx.x;
    int base = blockIdx.x * SCAN_CHUNK + t * 4;
    int s = 0;
#pragma unroll
    for (int j = 0; j < 4; ++j) {
        int i = base + j;
        if (i < n) s += cnt[i];
    }
    ls[t] = s;
    __syncthreads();
    for (int off = 128; off > 0; off >>= 1) {
        if (t < off) ls[t] += ls[t + off];
        __syncthreads();
    }
    if (t == 0) blockSums[blockIdx.x] = ls[0];
}

__global__ void scan_sums_kernel(int* __restrict__ blockSums, int nb,
                                 int* __restrict__ rowptr, int n, int total)
{
    int run = 0;
    for (int i = 0; i < nb; ++i) {
        int c = blockSums[i];
        blockSums[i] = run;
        run += c;
    }
    rowptr[n] = total;
}

__global__ __launch_bounds__(256) void scan_final_kernel(
    const int* __restrict__ cnt, const int* __restrict__ blockSums,
    int* __restrict__ rowptr, int* __restrict__ cursor, int n)
{
    __shared__ int ls[256];
    int t = threadIdx.x;
    int base = blockIdx.x * SCAN_CHUNK + t * 4;
    int v0 = (base + 0 < n) ? cnt[base + 0] : 0;
    int v1 = (base + 1 < n) ? cnt[base + 1] : 0;
    int v2 = (base + 2 < n) ? cnt[base + 2] : 0;
    int v3 = (base + 3 < n) ? cnt[base + 3] : 0;
    ls[t] = v0 + v1 + v2 + v3;
    __syncthreads();
    for (int off = 1; off < 256; off <<= 1) {
        int x = (t >= off) ? ls[t - off] : 0;
        __syncthreads();
        ls[t] += x;
        __syncthreads();
    }
    int prefix = blockSums[blockIdx.x] + (t ? ls[t - 1] : 0);
    int e0 = prefix;
    int e1 = e0 + v0;
    int e2 = e1 + v1;
    int e3 = e2 + v2;
    if (base + 0 < n) { rowptr[base + 0] = e0; cursor[base + 0] = e0; }
    if (base + 1 < n) { rowptr[base + 1] = e1; cursor[base + 1] = e1; }
    if (base + 2 < n) { rowptr[base + 2] = e2; cursor[base + 2] = e2; }
    if (base + 3 < n) { rowptr[base + 3] = e3; cursor[base + 3] = e3; }
}

__global__ __launch_bounds__(256) void scatter_edges_kernel(
    const int* __restrict__ rows, const int* __restrict__ cols,
    const float* __restrict__ vals, int* __restrict__ cursor,
    int2* __restrict__ spack, int nEdges, int rpg)
{
    const int g     = blockIdx.x & (NGROUP - 1);
    const int blkIn = blockIdx.x >> 3;
    const int nBlk  = gridDim.x >> 3;
    const int lo = g * rpg, hi = lo + rpg;
    const int stride = nBlk * blockDim.x;
    for (int e = blkIn * blockDim.x + threadIdx.x; e < nEdges; e += stride) {
        int r = rows[e];
        if (r >= lo && r < hi) {
            int pos = atomicAdd(&cursor[r], 1);
            spack[pos] = make_int2(cols[e], __float_as_int(vals[e]));
        }
    }
}

// ---------------------------------------------------------------------------
// CSR SpMM hop, bf16 src: one wave per row, quarter-wave per edge, lane =
// 4-channel group (8 B gather). Branchless clamped indices so both gathers
// issue unconditionally (v=0 masks OOB). fp32 accumulate, xor-reduce.
// ---------------------------------------------------------------------------
template<bool DST_F32>
__global__ __launch_bounds__(256) void spmm_csr_kernel(
    const int* __restrict__ rowptr, const int2* __restrict__ spack,
    const unsigned short* __restrict__ src, void* __restrict__ dstv, int n)
{
    const int row  = blockIdx.x * 4 + (threadIdx.x >> 6);
    const int lane = threadIdx.x & 63;
    if (row >= n) return;

    const int beg = rowptr[row];
    const int end = rowptr[row + 1];
    const int sub = lane >> 4;        // which edge of the group of 4
    const int ch  = (lane & 15) * 4;  // channel offset of this lane's group

    float4 acc = make_float4(0.f, 0.f, 0.f, 0.f);

    for (int b = beg; b < end; b += 8) {
        int e0 = b + sub;
        int e1 = b + 4 + sub;
        int2 p0 = spack[min(e0, end - 1)];
        int2 p1 = spack[min(e1, end - 1)];
        float v0 = (e0 < end) ? __int_as_float(p0.y) : 0.f;
        float v1 = (e1 < end) ? __int_as_float(p1.y) : 0.f;
        ushort4 s0 = *(const ushort4*)(src + ((size_t)p0.x << 6) + ch);
        ushort4 s1 = *(const ushort4*)(src + ((size_t)p1.x << 6) + ch);
        acc.x = fmaf(v0, bf2f(s0.x), acc.x);
        acc.y = fmaf(v0, bf2f(s0.y), acc.y);
        acc.z = fmaf(v0, bf2f(s0.z), acc.z);
        acc.w = fmaf(v0, bf2f(s0.w), acc.w);
        acc.x = fmaf(v1, bf2f(s1.x), acc.x);
        acc.y = fmaf(v1, bf2f(s1.y), acc.y);
        acc.z = fmaf(v1, bf2f(s1.z), acc.z);
        acc.w = fmaf(v1, bf2f(s1.w), acc.w);
    }

#pragma unroll
    for (int mask = 16; mask <= 32; mask <<= 1) {
        acc.x += __shfl_xor(acc.x, mask);
        acc.y += __shfl_xor(acc.y, mask);
        acc.z += __shfl_xor(acc.z, mask);
        acc.w += __shfl_xor(acc.w, mask);
    }

    if (lane < 16) {
        if constexpr (DST_F32) {
            *(float4*)((float*)dstv + ((size_t)row << 6) + ch) = acc;
        } else {
            ushort4 o;
            o.x = f2bf(acc.x);
            o.y = f2bf(acc.y);
            o.z = f2bf(acc.z);
            o.w = f2bf(acc.w);
            *(ushort4*)((unsigned short*)dstv + ((size_t)row << 6) + ch) = o;
        }
    }
}

// ---------------------------------------------------------------------------
extern "C" void kernel_launch(void* const* d_in, const int* in_sizes, int n_in,
                              void* d_out, int out_size, void* d_ws, size_t ws_size,
                              hipStream_t stream)
{
    const int*   adj  = (const int*)d_in[0];    // [2, E] int32
    const float* vals = (const float*)d_in[1];  // [E]
    const float* feat = (const float*)d_in[2];  // [N, 256]
    const float* W    = (const float*)d_in[3];  // [256, 64]
    const float* bias = (const float*)d_in[4];  // [1, 64]

    const int E = in_sizes[1];
    const int n = in_sizes[2] / IN_CH;
    const int* rows = adj;       // destination rows
    const int* cols = adj + E;   // gather sources

    // ---- workspace layout (256 B aligned regions) ----
    char* ws = (char*)d_ws;
    size_t off = 0;
    auto alloc = [&](size_t bytes) {
        void* p = ws + off;
        off += (bytes + 255) & ~(size_t)255;
        return p;
    };
    unsigned short* B0 = (unsigned short*)alloc((size_t)n * OUT_CH * sizeof(unsigned short));
    unsigned short* B1 = (unsigned short*)alloc((size_t)n * OUT_CH * sizeof(unsigned short));
    int*   rowptr    = (int*)  alloc((size_t)(n + 1) * sizeof(int));
    int*   cursor    = (int*)  alloc((size_t)n * sizeof(int));
    int2*  spack     = (int2*) alloc((size_t)E * sizeof(int2));
    int*   blockSums = (int*)  alloc(4096 * sizeof(int));

    float* out = (float*)d_out;

    const int rpg = (n + NGROUP - 1) / NGROUP;   // rows per XCD group

    // ---- build CSR ----
    hipMemsetAsync(cursor, 0, (size_t)n * sizeof(int), stream);
    hist_kernel<<<8192, 256, 0, stream>>>(rows, cursor, E, rpg);

    const int nb = (n + SCAN_CHUNK - 1) / SCAN_CHUNK;
    block_sum_kernel<<<nb, 256, 0, stream>>>(cursor, blockSums, n);
    scan_sums_kernel<<<1, 1, 0, stream>>>(blockSums, nb, rowptr, n, E);
    scan_final_kernel<<<nb, 256, 0, stream>>>(cursor, blockSums, rowptr, cursor, n);
    scatter_edges_kernel<<<8192, 256, 0, stream>>>(rows, cols, vals, cursor, spack, E, rpg);

    // ---- dense transform (bf16 output) ----
    gemm_relu_kernel<<<(n + 63) / 64, 256, 0, stream>>>(feat, W, bias, B0, n);

    // ---- 3 SpMM hops: B0 -> B1 -> B0 -> out(fp32) ----
    const int hblocks = (n + 3) / 4;
    spmm_csr_kernel<false><<<hblocks, 256, 0, stream>>>(rowptr, spack, B0, B1, n);
    spmm_csr_kernel<false><<<hblocks, 256, 0, stream>>>(rowptr, spack, B1, B0, n);
    spmm_csr_kernel<true><<<hblocks, 256, 0, stream>>>(rowptr, spack, B0, out, n);
}

// Round 6
// 467.550 us; speedup vs baseline: 2.6371x; 1.0403x over previous
//
#include <hip/hip_runtime.h>

#define IN_CH 256
#define OUT_CH 64
#define SCAN_CHUNK 1024   // elements per scan block (256 threads x 4)
#define NGROUP 8          // one group per XCD (blockIdx & 7 round-robin)

// ---- bf16 helpers (RNE) ----
__device__ __forceinline__ unsigned short f2bf(float f) {
    unsigned u = __float_as_uint(f);
    u += 0x7fff + ((u >> 16) & 1);
    return (unsigned short)(u >> 16);
}
__device__ __forceinline__ float bf2f(unsigned short h) {
    return __uint_as_float((unsigned)h << 16);
}

using bfrag = __attribute__((ext_vector_type(8))) short;   // 8 bf16 (4 VGPRs)
using ffrag = __attribute__((ext_vector_type(4))) float;   // 4 fp32 acc

// ---------------------------------------------------------------------------
// MFMA dense transform: B0[n][64] = bf16(relu(feat @ W + bias))
// Block = 256 thr = 4 waves; block tile 64 rows x 64 cols; wave = 16-row slab
// x 4 N-tiles of 16. K = 256 in 8 steps of 32 (v_mfma_f32_16x16x32_bf16).
// W staged once per block into LDS transposed bf16 Wt[n][k] (pad +8 ushort ->
// lane bank step 4, 2-way max aliasing ~ free). A-frags direct from global.
// Layouts (m89/m120 verified): A[m=lane&15][k=quad*8+j],
// B[k=quad*8+j][n=lane&15], C/D row=quad*4+reg col=lane&15.
// ---------------------------------------------------------------------------
#define WSTRIDE 264
__global__ __launch_bounds__(256) void gemm_mfma_kernel(
    const float* __restrict__ feat, const float* __restrict__ W,
    const float* __restrict__ bias, unsigned short* __restrict__ out, int n)
{
    __shared__ unsigned short Wt[64 * WSTRIDE];   // 33 KB

    // stage W -> LDS (bf16, transposed). Coalesced global reads.
    for (int i = threadIdx.x; i < IN_CH * OUT_CH; i += 256) {
        int k  = i >> 6;        // 0..255
        int nc = i & 63;        // 0..63
        Wt[nc * WSTRIDE + k] = f2bf(W[i]);
    }
    __syncthreads();

    const int wv   = threadIdx.x >> 6;
    const int lane = threadIdx.x & 63;
    const int quad = lane >> 4;
    const int lc   = lane & 15;

    const int arow = blockIdx.x * 64 + wv * 16 + lc;      // A-fragment row
    const int lrow = min(arow, n - 1);
    const float4* frow = (const float4*)(feat + (size_t)lrow * IN_CH);

    ffrag acc[4];
#pragma unroll
    for (int nt = 0; nt < 4; ++nt)
#pragma unroll
        for (int r = 0; r < 4; ++r) acc[nt][r] = 0.f;

#pragma unroll
    for (int ks = 0; ks < 8; ++ks) {
        const int k0 = ks * 32;
        float4 a0 = frow[(k0 >> 2) + quad * 2 + 0];
        float4 a1 = frow[(k0 >> 2) + quad * 2 + 1];
        bfrag af;
        af[0] = (short)f2bf(a0.x); af[1] = (short)f2bf(a0.y);
        af[2] = (short)f2bf(a0.z); af[3] = (short)f2bf(a0.w);
        af[4] = (short)f2bf(a1.x); af[5] = (short)f2bf(a1.y);
        af[6] = (short)f2bf(a1.z); af[7] = (short)f2bf(a1.w);
#pragma unroll
        for (int nt = 0; nt < 4; ++nt) {
            bfrag bf = *(const bfrag*)&Wt[(nt * 16 + lc) * WSTRIDE + k0 + quad * 8];
            acc[nt] = __builtin_amdgcn_mfma_f32_16x16x32_bf16(af, bf, acc[nt], 0, 0, 0);
        }
    }

    // epilogue: bias + relu + bf16 store. C/D: row=quad*4+r, col=lane&15.
#pragma unroll
    for (int nt = 0; nt < 4; ++nt) {
        float bv = bias[nt * 16 + lc];
#pragma unroll
        for (int r = 0; r < 4; ++r) {
            int orow = blockIdx.x * 64 + wv * 16 + quad * 4 + r;
            if (orow < n) {
                float v = fmaxf(acc[nt][r] + bv, 0.f);
                out[(size_t)orow * OUT_CH + nt * 16 + lc] = f2bf(v);
            }
        }
    }
}

// ---------------------------------------------------------------------------
// CSR build, XCD-localized (group g = blockIdx & 7 owns rows [g*rpg,(g+1)*rpg))
// ---------------------------------------------------------------------------
__global__ __launch_bounds__(256) void hist_kernel(
    const int* __restrict__ rows, int* __restrict__ cnt, int nEdges, int rpg)
{
    const int g     = blockIdx.x & (NGROUP - 1);
    const int blkIn = blockIdx.x >> 3;
    const int nBlk  = gridDim.x >> 3;
    const int lo = g * rpg, hi = lo + rpg;
    const int stride = nBlk * blockDim.x;
    for (int e = blkIn * blockDim.x + threadIdx.x; e < nEdges; e += stride) {
        int r = rows[e];
        if (r >= lo && r < hi) atomicAdd(&cnt[r], 1);
    }
}

__global__ __launch_bounds__(256) void block_sum_kernel(
    const int* __restrict__ cnt, int* __restrict__ blockSums, int n)
{
    __shared__ int ls[256];
    int t = threadIdx.x;
    int base = blockIdx.x * SCAN_CHUNK + t * 4;
    int s = 0;
#pragma unroll
    for (int j = 0; j < 4; ++j) {
        int i = base + j;
        if (i < n) s += cnt[i];
    }
    ls[t] = s;
    __syncthreads();
    for (int off = 128; off > 0; off >>= 1) {
        if (t < off) ls[t] += ls[t + off];
        __syncthreads();
    }
    if (t == 0) blockSums[blockIdx.x] = ls[0];
}

__global__ void scan_sums_kernel(int* __restrict__ blockSums, int nb,
                                 int* __restrict__ rowptr, int n, int total)
{
    int run = 0;
    for (int i = 0; i < nb; ++i) {
        int c = blockSums[i];
        blockSums[i] = run;
        run += c;
    }
    rowptr[n] = total;
}

__global__ __launch_bounds__(256) void scan_final_kernel(
    const int* __restrict__ cnt, const int* __restrict__ blockSums,
    int* __restrict__ rowptr, int* __restrict__ cursor, int n)
{
    __shared__ int ls[256];
    int t = threadIdx.x;
    int base = blockIdx.x * SCAN_CHUNK + t * 4;
    int v0 = (base + 0 < n) ? cnt[base + 0] : 0;
    int v1 = (base + 1 < n) ? cnt[base + 1] : 0;
    int v2 = (base + 2 < n) ? cnt[base + 2] : 0;
    int v3 = (base + 3 < n) ? cnt[base + 3] : 0;
    ls[t] = v0 + v1 + v2 + v3;
    __syncthreads();
    for (int off = 1; off < 256; off <<= 1) {
        int x = (t >= off) ? ls[t - off] : 0;
        __syncthreads();
        ls[t] += x;
        __syncthreads();
    }
    int prefix = blockSums[blockIdx.x] + (t ? ls[t - 1] : 0);
    int e0 = prefix;
    int e1 = e0 + v0;
    int e2 = e1 + v1;
    int e3 = e2 + v2;
    if (base + 0 < n) { rowptr[base + 0] = e0; cursor[base + 0] = e0; }
    if (base + 1 < n) { rowptr[base + 1] = e1; cursor[base + 1] = e1; }
    if (base + 2 < n) { rowptr[base + 2] = e2; cursor[base + 2] = e2; }
    if (base + 3 < n) { rowptr[base + 3] = e3; cursor[base + 3] = e3; }
}

__global__ __launch_bounds__(256) void scatter_edges_kernel(
    const int* __restrict__ rows, const int* __restrict__ cols,
    const float* __restrict__ vals, int* __restrict__ cursor,
    int2* __restrict__ spack, int nEdges, int rpg)
{
    const int g     = blockIdx.x & (NGROUP - 1);
    const int blkIn = blockIdx.x >> 3;
    const int nBlk  = gridDim.x >> 3;
    const int lo = g * rpg, hi = lo + rpg;
    const int stride = nBlk * blockDim.x;
    for (int e = blkIn * blockDim.x + threadIdx.x; e < nEdges; e += stride) {
        int r = rows[e];
        if (r >= lo && r < hi) {
            int pos = atomicAdd(&cursor[r], 1);
            spack[pos] = make_int2(cols[e], __float_as_int(vals[e]));
        }
    }
}

// ---------------------------------------------------------------------------
// CSR SpMM hop, bf16 src: one wave per row, quarter-wave per edge, lane =
// 4-channel group (8 B gather). Branchless clamped indices. fp32 accumulate,
// 2-step xor-reduce, coalesced store.
// ---------------------------------------------------------------------------
template<bool DST_F32>
__global__ __launch_bounds__(256) void spmm_csr_kernel(
    const int* __restrict__ rowptr, const int2* __restrict__ spack,
    const unsigned short* __restrict__ src, void* __restrict__ dstv, int n)
{
    const int row  = blockIdx.x * 4 + (threadIdx.x >> 6);
    const int lane = threadIdx.x & 63;
    if (row >= n) return;

    const int beg = rowptr[row];
    const int end = rowptr[row + 1];
    const int sub = lane >> 4;
    const int ch  = (lane & 15) * 4;

    float4 acc = make_float4(0.f, 0.f, 0.f, 0.f);

    for (int b = beg; b < end; b += 8) {
        int e0 = b + sub;
        int e1 = b + 4 + sub;
        int2 p0 = spack[min(e0, end - 1)];
        int2 p1 = spack[min(e1, end - 1)];
        float v0 = (e0 < end) ? __int_as_float(p0.y) : 0.f;
        float v1 = (e1 < end) ? __int_as_float(p1.y) : 0.f;
        ushort4 s0 = *(const ushort4*)(src + ((size_t)p0.x << 6) + ch);
        ushort4 s1 = *(const ushort4*)(src + ((size_t)p1.x << 6) + ch);
        acc.x = fmaf(v0, bf2f(s0.x), acc.x);
        acc.y = fmaf(v0, bf2f(s0.y), acc.y);
        acc.z = fmaf(v0, bf2f(s0.z), acc.z);
        acc.w = fmaf(v0, bf2f(s0.w), acc.w);
        acc.x = fmaf(v1, bf2f(s1.x), acc.x);
        acc.y = fmaf(v1, bf2f(s1.y), acc.y);
        acc.z = fmaf(v1, bf2f(s1.z), acc.z);
        acc.w = fmaf(v1, bf2f(s1.w), acc.w);
    }

#pragma unroll
    for (int mask = 16; mask <= 32; mask <<= 1) {
        acc.x += __shfl_xor(acc.x, mask);
        acc.y += __shfl_xor(acc.y, mask);
        acc.z += __shfl_xor(acc.z, mask);
        acc.w += __shfl_xor(acc.w, mask);
    }

    if (lane < 16) {
        if constexpr (DST_F32) {
            *(float4*)((float*)dstv + ((size_t)row << 6) + ch) = acc;
        } else {
            ushort4 o;
            o.x = f2bf(acc.x);
            o.y = f2bf(acc.y);
            o.z = f2bf(acc.z);
            o.w = f2bf(acc.w);
            *(ushort4*)((unsigned short*)dstv + ((size_t)row << 6) + ch) = o;
        }
    }
}

// ---------------------------------------------------------------------------
extern "C" void kernel_launch(void* const* d_in, const int* in_sizes, int n_in,
                              void* d_out, int out_size, void* d_ws, size_t ws_size,
                              hipStream_t stream)
{
    const int*   adj  = (const int*)d_in[0];    // [2, E] int32
    const float* vals = (const float*)d_in[1];  // [E]
    const float* feat = (const float*)d_in[2];  // [N, 256]
    const float* W    = (const float*)d_in[3];  // [256, 64]
    const float* bias = (const float*)d_in[4];  // [1, 64]

    const int E = in_sizes[1];
    const int n = in_sizes[2] / IN_CH;
    const int* rows = adj;       // destination rows
    const int* cols = adj + E;   // gather sources

    // ---- workspace layout (256 B aligned regions) ----
    char* ws = (char*)d_ws;
    size_t off = 0;
    auto alloc = [&](size_t bytes) {
        void* p = ws + off;
        off += (bytes + 255) & ~(size_t)255;
        return p;
    };
    unsigned short* B0 = (unsigned short*)alloc((size_t)n * OUT_CH * sizeof(unsigned short));
    unsigned short* B1 = (unsigned short*)alloc((size_t)n * OUT_CH * sizeof(unsigned short));
    int*   rowptr    = (int*)  alloc((size_t)(n + 1) * sizeof(int));
    int*   cursor    = (int*)  alloc((size_t)n * sizeof(int));
    int2*  spack     = (int2*) alloc((size_t)E * sizeof(int2));
    int*   blockSums = (int*)  alloc(4096 * sizeof(int));

    float* out = (float*)d_out;

    const int rpg = (n + NGROUP - 1) / NGROUP;   // rows per XCD group

    // ---- build CSR ----
    hipMemsetAsync(cursor, 0, (size_t)n * sizeof(int), stream);
    hist_kernel<<<8192, 256, 0, stream>>>(rows, cursor, E, rpg);

    const int nb = (n + SCAN_CHUNK - 1) / SCAN_CHUNK;
    block_sum_kernel<<<nb, 256, 0, stream>>>(cursor, blockSums, n);
    scan_sums_kernel<<<1, 1, 0, stream>>>(blockSums, nb, rowptr, n, E);
    scan_final_kernel<<<nb, 256, 0, stream>>>(cursor, blockSums, rowptr, cursor, n);
    scatter_edges_kernel<<<8192, 256, 0, stream>>>(rows, cols, vals, cursor, spack, E, rpg);

    // ---- dense transform (MFMA, bf16 output) ----
    gemm_mfma_kernel<<<(n + 63) / 64, 256, 0, stream>>>(feat, W, bias, B0, n);

    // ---- 3 SpMM hops: B0 -> B1 -> B0 -> out(fp32) ----
    const int hblocks = (n + 3) / 4;
    spmm_csr_kernel<false><<<hblocks, 256, 0, stream>>>(rowptr, spack, B0, B1, n);
    spmm_csr_kernel<false><<<hblocks, 256, 0, stream>>>(rowptr, spack, B1, B0, n);
    spmm_csr_kernel<true><<<hblocks, 256, 0, stream>>>(rowptr, spack, B0, out, n);
}

// Round 7
// 465.986 us; speedup vs baseline: 2.6459x; 1.0034x over previous
//
#include <hip/hip_runtime.h>

#define IN_CH 256
#define OUT_CH 64
#define SCAN_CHUNK 1024   // elements per scan block (256 threads x 4)
#define NGROUP 8          // one group per XCD (blockIdx & 7 round-robin)

// ---- bf16 helpers (RNE) ----
__device__ __forceinline__ unsigned short f2bf(float f) {
    unsigned u = __float_as_uint(f);
    u += 0x7fff + ((u >> 16) & 1);
    return (unsigned short)(u >> 16);
}
__device__ __forceinline__ float bf2f(unsigned short h) {
    return __uint_as_float((unsigned)h << 16);
}

using bfrag = __attribute__((ext_vector_type(8))) short;   // 8 bf16 (4 VGPRs)
using ffrag = __attribute__((ext_vector_type(4))) float;   // 4 fp32 acc

// ---------------------------------------------------------------------------
// MFMA dense transform: B0[n][64] = bf16(relu(feat @ W + bias))
// Fragment-major LDS: Wl[((ks*4+nt)*64 + lane)*8 + j] holds
// W[ks*32 + (lane>>4)*8 + j][nt*16 + (lane&15)] as bf16. Main-loop read is
// base + lane*16B -> canonical conflict-free ds_read_b128.
// Layouts (verified by R6 pass): A[m=lane&15][k=quad*8+j],
// B[k=quad*8+j][n=lane&15], C/D row=quad*4+r col=lane&15.
// ---------------------------------------------------------------------------
__global__ __launch_bounds__(256) void gemm_mfma_kernel(
    const float* __restrict__ feat, const float* __restrict__ W,
    const float* __restrict__ bias, unsigned short* __restrict__ out, int n)
{
    __shared__ unsigned short Wl[IN_CH * OUT_CH / 8 * 8];   // 32 KB

    // stage W -> LDS in fragment-major order (coalesced global reads)
    for (int i = threadIdx.x; i < IN_CH * OUT_CH; i += 256) {
        int k  = i >> 6;          // 0..255
        int c  = i & 63;          // 0..63
        int ks = k >> 5;
        int kq = (k >> 3) & 3;
        int j  = k & 7;
        int nt = c >> 4;
        int lc = c & 15;
        Wl[(((ks * 4 + nt) * 64) + kq * 16 + lc) * 8 + j] = f2bf(W[i]);
    }
    __syncthreads();

    const int wv   = threadIdx.x >> 6;
    const int lane = threadIdx.x & 63;
    const int quad = lane >> 4;
    const int lc   = lane & 15;

    const int arow = blockIdx.x * 64 + wv * 16 + lc;      // A-fragment row
    const int lrow = min(arow, n - 1);
    const float4* frow = (const float4*)(feat + (size_t)lrow * IN_CH);

    ffrag acc[4];
#pragma unroll
    for (int nt = 0; nt < 4; ++nt)
#pragma unroll
        for (int r = 0; r < 4; ++r) acc[nt][r] = 0.f;

#pragma unroll
    for (int ks = 0; ks < 8; ++ks) {
        const int k0 = ks * 32;
        float4 a0 = frow[(k0 >> 2) + quad * 2 + 0];
        float4 a1 = frow[(k0 >> 2) + quad * 2 + 1];
        bfrag af;
        af[0] = (short)f2bf(a0.x); af[1] = (short)f2bf(a0.y);
        af[2] = (short)f2bf(a0.z); af[3] = (short)f2bf(a0.w);
        af[4] = (short)f2bf(a1.x); af[5] = (short)f2bf(a1.y);
        af[6] = (short)f2bf(a1.z); af[7] = (short)f2bf(a1.w);
#pragma unroll
        for (int nt = 0; nt < 4; ++nt) {
            bfrag bf = *(const bfrag*)&Wl[(((ks * 4 + nt) * 64) + lane) * 8];
            acc[nt] = __builtin_amdgcn_mfma_f32_16x16x32_bf16(af, bf, acc[nt], 0, 0, 0);
        }
    }

    // epilogue: bias + relu + bf16 store. C/D: row=quad*4+r, col=lane&15.
#pragma unroll
    for (int nt = 0; nt < 4; ++nt) {
        float bv = bias[nt * 16 + lc];
#pragma unroll
        for (int r = 0; r < 4; ++r) {
            int orow = blockIdx.x * 64 + wv * 16 + quad * 4 + r;
            if (orow < n) {
                float v = fmaxf(acc[nt][r] + bv, 0.f);
                out[(size_t)orow * OUT_CH + nt * 16 + lc] = f2bf(v);
            }
        }
    }
}

// ---------------------------------------------------------------------------
// CSR build, XCD-localized. Edge streams use nontemporal loads so the 8x
// re-read does NOT pollute L2 -> spack/cnt lines stay resident and merge.
// ---------------------------------------------------------------------------
__global__ __launch_bounds__(256) void hist_kernel(
    const int* __restrict__ rows, int* __restrict__ cnt, int nEdges, int rpg)
{
    const int g     = blockIdx.x & (NGROUP - 1);
    const int blkIn = blockIdx.x >> 3;
    const int nBlk  = gridDim.x >> 3;
    const int lo = g * rpg, hi = lo + rpg;
    const int stride = nBlk * blockDim.x;
    for (int e = blkIn * blockDim.x + threadIdx.x; e < nEdges; e += stride) {
        int r = __builtin_nontemporal_load(rows + e);
        if (r >= lo && r < hi) atomicAdd(&cnt[r], 1);
    }
}

__global__ __launch_bounds__(256) void block_sum_kernel(
    const int* __restrict__ cnt, int* __restrict__ blockSums, int n)
{
    __shared__ int ls[256];
    int t = threadIdx.x;
    int base = blockIdx.x * SCAN_CHUNK + t * 4;
    int s = 0;
#pragma unroll
    for (int j = 0; j < 4; ++j) {
        int i = base + j;
        if (i < n) s += cnt[i];
    }
    ls[t] = s;
    __syncthreads();
    for (int off = 128; off > 0; off >>= 1) {
        if (t < off) ls[t] += ls[t + off];
        __syncthreads();
    }
    if (t == 0) blockSums[blockIdx.x] = ls[0];
}

__global__ void scan_sums_kernel(int* __restrict__ blockSums, int nb,
                                 int* __restrict__ rowptr, int n, int total)
{
    int run = 0;
    for (int i = 0; i < nb; ++i) {
        int c = blockSums[i];
        blockSums[i] = run;
        run += c;
    }
    rowptr[n] = total;
}

__global__ __launch_bounds__(256) void scan_final_kernel(
    const int* __restrict__ cnt, const int* __restrict__ blockSums,
    int* __restrict__ rowptr, int* __restrict__ cursor, int n)
{
    __shared__ int ls[256];
    int t = threadIdx.x;
    int base = blockIdx.x * SCAN_CHUNK + t * 4;
    int v0 = (base + 0 < n) ? cnt[base + 0] : 0;
    int v1 = (base + 1 < n) ? cnt[base + 1] : 0;
    int v2 = (base + 2 < n) ? cnt[base + 2] : 0;
    int v3 = (base + 3 < n) ? cnt[base + 3] : 0;
    ls[t] = v0 + v1 + v2 + v3;
    __syncthreads();
    for (int off = 1; off < 256; off <<= 1) {
        int x = (t >= off) ? ls[t - off] : 0;
        __syncthreads();
        ls[t] += x;
        __syncthreads();
    }
    int prefix = blockSums[blockIdx.x] + (t ? ls[t - 1] : 0);
    int e0 = prefix;
    int e1 = e0 + v0;
    int e2 = e1 + v1;
    int e3 = e2 + v2;
    if (base + 0 < n) { rowptr[base + 0] = e0; cursor[base + 0] = e0; }
    if (base + 1 < n) { rowptr[base + 1] = e1; cursor[base + 1] = e1; }
    if (base + 2 < n) { rowptr[base + 2] = e2; cursor[base + 2] = e2; }
    if (base + 3 < n) { rowptr[base + 3] = e3; cursor[base + 3] = e3; }
}

__global__ __launch_bounds__(256) void scatter_edges_kernel(
    const int* __restrict__ rows, const int* __restrict__ cols,
    const float* __restrict__ vals, int* __restrict__ cursor,
    int2* __restrict__ spack, int nEdges, int rpg)
{
    const int g     = blockIdx.x & (NGROUP - 1);
    const int blkIn = blockIdx.x >> 3;
    const int nBlk  = gridDim.x >> 3;
    const int lo = g * rpg, hi = lo + rpg;
    const int stride = nBlk * blockDim.x;
    for (int e = blkIn * blockDim.x + threadIdx.x; e < nEdges; e += stride) {
        int r = __builtin_nontemporal_load(rows + e);
        if (r >= lo && r < hi) {
            int   c = __builtin_nontemporal_load(cols + e);
            float v = __builtin_nontemporal_load(vals + e);
            int pos = atomicAdd(&cursor[r], 1);
            spack[pos] = make_int2(c, __float_as_int(v));
        }
    }
}

// ---------------------------------------------------------------------------
// CSR SpMM hop, bf16 src: one wave per row, quarter-wave per edge, lane =
// 4-channel group (8 B gather). 16 edges in flight per iteration (4
// independent spack->gather chains). fp32 accumulate, xor-reduce epilogue.
// ---------------------------------------------------------------------------
template<bool DST_F32>
__global__ __launch_bounds__(256) void spmm_csr_kernel(
    const int* __restrict__ rowptr, const int2* __restrict__ spack,
    const unsigned short* __restrict__ src, void* __restrict__ dstv, int n)
{
    const int row  = blockIdx.x * 4 + (threadIdx.x >> 6);
    const int lane = threadIdx.x & 63;
    if (row >= n) return;

    const int beg = rowptr[row];
    const int end = rowptr[row + 1];
    const int sub = lane >> 4;
    const int ch  = (lane & 15) * 4;

    float4 acc0 = make_float4(0.f, 0.f, 0.f, 0.f);
    float4 acc1 = make_float4(0.f, 0.f, 0.f, 0.f);

    for (int b = beg; b < end; b += 16) {
        int e0 = b + sub;
        int e1 = b + 4 + sub;
        int e2 = b + 8 + sub;
        int e3 = b + 12 + sub;
        int2 p0 = spack[min(e0, end - 1)];
        int2 p1 = spack[min(e1, end - 1)];
        int2 p2 = spack[min(e2, end - 1)];
        int2 p3 = spack[min(e3, end - 1)];
        float v0 = (e0 < end) ? __int_as_float(p0.y) : 0.f;
        float v1 = (e1 < end) ? __int_as_float(p1.y) : 0.f;
        float v2 = (e2 < end) ? __int_as_float(p2.y) : 0.f;
        float v3 = (e3 < end) ? __int_as_float(p3.y) : 0.f;
        ushort4 s0 = *(const ushort4*)(src + ((size_t)p0.x << 6) + ch);
        ushort4 s1 = *(const ushort4*)(src + ((size_t)p1.x << 6) + ch);
        ushort4 s2 = *(const ushort4*)(src + ((size_t)p2.x << 6) + ch);
        ushort4 s3 = *(const ushort4*)(src + ((size_t)p3.x << 6) + ch);
        acc0.x = fmaf(v0, bf2f(s0.x), acc0.x);
        acc0.y = fmaf(v0, bf2f(s0.y), acc0.y);
        acc0.z = fmaf(v0, bf2f(s0.z), acc0.z);
        acc0.w = fmaf(v0, bf2f(s0.w), acc0.w);
        acc1.x = fmaf(v1, bf2f(s1.x), acc1.x);
        acc1.y = fmaf(v1, bf2f(s1.y), acc1.y);
        acc1.z = fmaf(v1, bf2f(s1.z), acc1.z);
        acc1.w = fmaf(v1, bf2f(s1.w), acc1.w);
        acc0.x = fmaf(v2, bf2f(s2.x), acc0.x);
        acc0.y = fmaf(v2, bf2f(s2.y), acc0.y);
        acc0.z = fmaf(v2, bf2f(s2.z), acc0.z);
        acc0.w = fmaf(v2, bf2f(s2.w), acc0.w);
        acc1.x = fmaf(v3, bf2f(s3.x), acc1.x);
        acc1.y = fmaf(v3, bf2f(s3.y), acc1.y);
        acc1.z = fmaf(v3, bf2f(s3.z), acc1.z);
        acc1.w = fmaf(v3, bf2f(s3.w), acc1.w);
    }

    float4 acc = make_float4(acc0.x + acc1.x, acc0.y + acc1.y,
                             acc0.z + acc1.z, acc0.w + acc1.w);

#pragma unroll
    for (int mask = 16; mask <= 32; mask <<= 1) {
        acc.x += __shfl_xor(acc.x, mask);
        acc.y += __shfl_xor(acc.y, mask);
        acc.z += __shfl_xor(acc.z, mask);
        acc.w += __shfl_xor(acc.w, mask);
    }

    if (lane < 16) {
        if constexpr (DST_F32) {
            *(float4*)((float*)dstv + ((size_t)row << 6) + ch) = acc;
        } else {
            ushort4 o;
            o.x = f2bf(acc.x);
            o.y = f2bf(acc.y);
            o.z = f2bf(acc.z);
            o.w = f2bf(acc.w);
            *(ushort4*)((unsigned short*)dstv + ((size_t)row << 6) + ch) = o;
        }
    }
}

// ---------------------------------------------------------------------------
extern "C" void kernel_launch(void* const* d_in, const int* in_sizes, int n_in,
                              void* d_out, int out_size, void* d_ws, size_t ws_size,
                              hipStream_t stream)
{
    const int*   adj  = (const int*)d_in[0];    // [2, E] int32
    const float* vals = (const float*)d_in[1];  // [E]
    const float* feat = (const float*)d_in[2];  // [N, 256]
    const float* W    = (const float*)d_in[3];  // [256, 64]
    const float* bias = (const float*)d_in[4];  // [1, 64]

    const int E = in_sizes[1];
    const int n = in_sizes[2] / IN_CH;
    const int* rows = adj;       // destination rows
    const int* cols = adj + E;   // gather sources

    // ---- workspace layout (256 B aligned regions) ----
    char* ws = (char*)d_ws;
    size_t off = 0;
    auto alloc = [&](size_t bytes) {
        void* p = ws + off;
        off += (bytes + 255) & ~(size_t)255;
        return p;
    };
    unsigned short* B0 = (unsigned short*)alloc((size_t)n * OUT_CH * sizeof(unsigned short));
    unsigned short* B1 = (unsigned short*)alloc((size_t)n * OUT_CH * sizeof(unsigned short));
    int*   rowptr    = (int*)  alloc((size_t)(n + 1) * sizeof(int));
    int*   cursor    = (int*)  alloc((size_t)n * sizeof(int));
    int2*  spack     = (int2*) alloc((size_t)E * sizeof(int2));
    int*   blockSums = (int*)  alloc(4096 * sizeof(int));

    float* out = (float*)d_out;

    const int rpg = (n + NGROUP - 1) / NGROUP;   // rows per XCD group

    // ---- build CSR ----
    hipMemsetAsync(cursor, 0, (size_t)n * sizeof(int), stream);
    hist_kernel<<<8192, 256, 0, stream>>>(rows, cursor, E, rpg);

    const int nb = (n + SCAN_CHUNK - 1) / SCAN_CHUNK;
    block_sum_kernel<<<nb, 256, 0, stream>>>(cursor, blockSums, n);
    scan_sums_kernel<<<1, 1, 0, stream>>>(blockSums, nb, rowptr, n, E);
    scan_final_kernel<<<nb, 256, 0, stream>>>(cursor, blockSums, rowptr, cursor, n);
    scatter_edges_kernel<<<8192, 256, 0, stream>>>(rows, cols, vals, cursor, spack, E, rpg);

    // ---- dense transform (MFMA, bf16 output) ----
    gemm_mfma_kernel<<<(n + 63) / 64, 256, 0, stream>>>(feat, W, bias, B0, n);

    // ---- 3 SpMM hops: B0 -> B1 -> B0 -> out(fp32) ----
    const int hblocks = (n + 3) / 4;
    spmm_csr_kernel<false><<<hblocks, 256, 0, stream>>>(rowptr, spack, B0, B1, n);
    spmm_csr_kernel<false><<<hblocks, 256, 0, stream>>>(rowptr, spack, B1, B0, n);
    spmm_csr_kernel<true><<<hblocks, 256, 0, stream>>>(rowptr, spack, B0, out, n);
}